// Round 5
// baseline (6933.346 us; speedup 1.0000x reference)
//
#include <hip/hip_runtime.h>
#include <hip/hip_bf16.h>
#include <hip/hip_cooperative_groups.h>

namespace cg = cooperative_groups;

// ---------------------------------------------------------------------------
// 2-layer LSTM decoder, B=64, T=25, H=2048, IN=OUT=66, hardtanh feedback.
// v10: persistent cooperative kernel, SAFE occupancy margin. v9 (512x512,
// 64KB LDS) needed exactly 2 blocks/CU with zero slack -> cooperative launch
// validation failed -> all-zero output (absmax 0.1338 == max|ref|). v10 uses
// 512 blocks x 256 threads, 32KB LDS, launch_bounds(256,4): occupancy bound
// 4 blocks/CU -> max coop grid 1024 >= 512 asked (2x margin).
// Phases per step (grid.sync between): P (gp0=h0@Whh0 on blocks 0..255,
// gp1=h1@Whh1 on 256..511, FC dots over all 2048 waves) -> C0 (blocks 0..255:
// x@Wih0+gp0 -> cell0 -> h0) -> C1 (blocks 256..511: h0@Wih1+gp1 -> cell1
// -> h1). Cell state lives in 2 registers/thread for all 25 steps.
// ---------------------------------------------------------------------------

typedef short bfrag  __attribute__((ext_vector_type(8)));   // 8 bf16 (4 VGPR)
typedef float accv   __attribute__((ext_vector_type(4)));   // 4 fp32 acc
typedef float vfloat4 __attribute__((ext_vector_type(4)));
typedef unsigned short usvec8 __attribute__((ext_vector_type(8)));

#define LD8(p) (*(const bfrag*)(p))

__device__ __forceinline__ unsigned short f2bf(float x) {
    unsigned int u = __float_as_uint(x);
    unsigned int r = u + 0x7FFFu + ((u >> 16) & 1u);   // RTNE
    return (unsigned short)(r >> 16);
}
__device__ __forceinline__ float bf2f(unsigned short u) {
    return __uint_as_float(((unsigned int)u) << 16);
}

// Activation fragment layout ("Ap", KC chunks of 32 k-elements):
//   (b, k) -> [((b>>4)*KC + (k>>5))*512 + (((k>>3)&3)*16 + (b&15))*8 + (k&7)]
__device__ __forceinline__ int ap_idx(int b, int j, int KC) {
    return (((b >> 4) * KC + (j >> 5)) << 9) + ((((j >> 3) & 3) * 16 + (b & 15)) << 3) + (j & 7);
}

// Weight fragment layout ("Bp"): n-tile (jb,p) holds rows
//   row = (2p + (n>>3))*2048 + jb*8 + (n&7),  n = lane&15
//   element at [((jb*2+p)*KC + kc)*512 + lane*8 + j],  k = kc*32 + (lane>>4)*8 + j

// ------------------- combined weight cast + state init ---------------------
__global__ __launch_bounds__(256) void prep(
        const float* __restrict__ s0, const float* __restrict__ s1, const float* __restrict__ s2,
        unsigned short* __restrict__ d0, unsigned short* __restrict__ d1, unsigned short* __restrict__ d2,
        const float* __restrict__ inputs, const float* __restrict__ hiddens,
        const float* __restrict__ cells,  const float* __restrict__ wih0,
        unsigned short* __restrict__ wih0p,
        unsigned short* __restrict__ h0, unsigned short* __restrict__ h1,
        float* __restrict__ c0, float* __restrict__ c1,
        unsigned short* __restrict__ xb,
        float* __restrict__ bsum0, float* __restrict__ bsum1,
        const float* __restrict__ bih0, const float* __restrict__ bhh0,
        const float* __restrict__ bih1, const float* __restrict__ bhh1) {
    int bid = blockIdx.x;
    if (bid < 24576) {                       // big-weight cast+permute
        unsigned int tid = bid * 256 + threadIdx.x;     // 0 .. 6291455
        unsigned int a = tid >> 21;                     // 2097152 frags per matrix
        unsigned int r = tid & 2097151u;
        const float* src = (a == 0) ? s0 : (a == 1) ? s1 : s2;
        unsigned short* dst = (a == 0) ? d0 : (a == 1) ? d1 : d2;
        unsigned int lane = r & 63u;
        unsigned int kc   = (r >> 6) & 63u;
        unsigned int p    = (r >> 12) & 1u;
        unsigned int jb   = r >> 13;
        unsigned int n = lane & 15u, quad = lane >> 4;
        unsigned int row = (2u * p + (n >> 3)) * 2048u + jb * 8u + (n & 7u);
        unsigned int k0  = kc * 32u + quad * 8u;
        const float* sp = src + (size_t)row * 2048 + k0;
        vfloat4 v0 = *(const vfloat4*)sp;
        vfloat4 v1 = *(const vfloat4*)(sp + 4);
        usvec8 u = { f2bf(v0.x), f2bf(v0.y), f2bf(v0.z), f2bf(v0.w),
                     f2bf(v1.x), f2bf(v1.y), f2bf(v1.z), f2bf(v1.w) };
        *(usvec8*)(dst + (size_t)r * 8) = u;
        return;
    }
    int i = (bid - 24576) * 256 + threadIdx.x;
    if (i < 786432) {                        // Wih0 pad-permute: [8192][66] -> Bp KC=3
        int jo = i & 7, lane = (i >> 3) & 63;
        int t2 = i >> 9, kc = t2 % 3, t3 = t2 / 3, p = t3 & 1, jb = t3 >> 1;
        int n = lane & 15, quad = lane >> 4;
        int row = (2 * p + (n >> 3)) * 2048 + jb * 8 + (n & 7);
        int k = kc * 32 + quad * 8 + jo;
        wih0p[i] = (k < 66) ? f2bf(wih0[row * 66 + k]) : (unsigned short)0;
        return;
    }
    i -= 786432;
    if (i < 131072) { int b = i >> 11, j = i & 2047; h0[ap_idx(b, j, 64)] = f2bf(hiddens[i]); return; }
    i -= 131072;
    if (i < 131072) { int b = i >> 11, j = i & 2047; h1[ap_idx(b, j, 64)] = f2bf(hiddens[131072 + i]); return; }
    i -= 131072;
    if (i < 131072) { int b = i >> 11, j = i & 2047; c0[(j >> 3) * 512 + b * 8 + (j & 7)] = cells[i]; return; }
    i -= 131072;
    if (i < 131072) { int b = i >> 11, j = i & 2047; c1[(j >> 3) * 512 + b * 8 + (j & 7)] = cells[131072 + i]; return; }
    i -= 131072;
    if (i < 6144) {                          // x pad-permute -> Ap KC=3
        int jo = i & 7, lane = (i >> 3) & 63;
        int t2 = i >> 9, kc = t2 % 3, m = t2 / 3;
        int b = m * 16 + (lane & 15);
        int k = kc * 32 + (lane >> 4) * 8 + jo;
        xb[i] = (k < 66) ? f2bf(inputs[b * 66 + k]) : (unsigned short)0;
        return;
    }
    i -= 6144;
    if (i < 8192) { bsum0[i] = bih0[i] + bhh0[i]; return; }
    i -= 8192;
    if (i < 8192) { bsum1[i] = bih1[i] + bhh1[i]; }
}

// ---- shared GEMM body: NW waves, 64/NW chunks/wave, PA=2 / PB=4, KC=64 ----
template<int NW>
__device__ __forceinline__ void gemmK(const unsigned short* __restrict__ Ap,
                                      const unsigned short* __restrict__ Bp,
                                      int jb, int lane, int w, accv (&acc)[4][2]) {
    constexpr int NC = 64 / NW, PA = 2, PB = 4;
    const unsigned short* a = Ap + ((size_t)w << 9) + lane * 8;
    const unsigned short* b = Bp + (((size_t)(2 * jb) * 64 + w) << 9) + lane * 8;
    bfrag fA[PA][4], fB[PB][2];
    auto issueA = [&](int i) {
        int s = i % PA;
        const unsigned short* ap = a + ((size_t)(i * NW) << 9);
        fA[s][0] = LD8(ap);
        fA[s][1] = LD8(ap + (64 << 9));
        fA[s][2] = LD8(ap + 2 * (64 << 9));
        fA[s][3] = LD8(ap + 3 * (64 << 9));
    };
    auto issueB = [&](int i) {
        int s = i % PB;
        const unsigned short* bp = b + ((size_t)(i * NW) << 9);
        fB[s][0] = LD8(bp);
        fB[s][1] = LD8(bp + (64 << 9));
    };
    #pragma unroll
    for (int i = 0; i < PB; ++i) issueB(i);                 // weight stream deep
    #pragma unroll
    for (int i = 0; i < PA; ++i) issueA(i);
    #pragma unroll
    for (int i = 0; i < NC; ++i) {
        int sa = i % PA, sb = i % PB;
        #pragma unroll
        for (int mi = 0; mi < 4; ++mi)
            #pragma unroll
            for (int p = 0; p < 2; ++p)
                acc[mi][p] = __builtin_amdgcn_mfma_f32_16x16x32_bf16(fA[sa][mi], fB[sb][p], acc[mi][p], 0, 0, 0);
        if (i + PA < NC) issueA(i + PA);
        if (i + PB < NC) issueB(i + PB);
    }
}

__device__ __forceinline__ void store_gsm(float (*gsm)[64][32], accv (&acc)[4][2],
                                          int lane, int w) {
    int n = lane & 15, quad = lane >> 4;
    #pragma unroll
    for (int mi = 0; mi < 4; ++mi)
        #pragma unroll
        for (int p = 0; p < 2; ++p)
            #pragma unroll
            for (int r = 0; r < 4; ++r) {
                int R = mi * 16 + quad * 4 + r;          // batch
                int C = p * 16 + n;                      // gate*8 + unit
                gsm[w][R][C ^ ((R & 3) << 3)] = acc[mi][p][r];
            }
}

// ------------------- persistent loop kernel (cooperative) ------------------
// 512 blocks x 256 threads, 32KB LDS, <=128 VGPR -> occupancy cap 4/CU,
// cooperative max grid 1024 >= 512 requested (2x validation margin).
__global__ __launch_bounds__(256, 4) void loopk(
        const unsigned short* __restrict__ whh0p, const unsigned short* __restrict__ whh1p,
        const unsigned short* __restrict__ wih0p, const unsigned short* __restrict__ wih1p,
        unsigned short* __restrict__ h0, unsigned short* __restrict__ h1,
        float* __restrict__ c0g, float* __restrict__ c1g,
        const float* __restrict__ bsum0, const float* __restrict__ bsum1,
        float* __restrict__ gp0, float* __restrict__ gp1,
        unsigned short* __restrict__ xb,
        const float* __restrict__ fcw, const float* __restrict__ fcb,
        float* __restrict__ outg) {
    __shared__ float gsm[4][64][32];
    cg::grid_group grid = cg::this_grid();
    int tid = threadIdx.x, lane = tid & 63, w = tid >> 6;   // w = 0..3
    int bid = blockIdx.x;
    int l  = bid >> 8;                       // 0: layer0 duty, 1: layer1 duty
    int jb = bid & 255;

    // this block's 512 cell elements live in 2 registers per thread
    const float* cst = l ? c1g : c0g;
    float creg0 = cst[jb * 512 + tid];
    float creg1 = cst[jb * 512 + 256 + tid];

    for (int t = 0; ; ++t) {
        // ---------------- phase P ----------------
        if (t < 25) {
            const unsigned short* Ap = l ? h1 : h0;
            const unsigned short* Bp = l ? whh1p : whh0p;
            float* gp = l ? gp1 : gp0;
            accv acc[4][2] = {};
            gemmK<4>(Ap, Bp, jb, lane, w, acc);
            store_gsm(gsm, acc, lane, w);
            __syncthreads();
            for (int idx = tid; idx < 2048; idx += 256) {
                int b = idx >> 5, C = idx & 31;
                int Cs = C ^ ((b & 3) << 3);
                float s = gsm[0][b][Cs] + gsm[1][b][Cs] + gsm[2][b][Cs] + gsm[3][b][Cs];
                gp[(size_t)jb * 2048 + idx] = s;
            }
        }
        if (t > 0) {                         // FC dots: 4224 = 66*64, 2048 waves
            for (int idx = bid * 4 + w; idx < 4224; idx += 2048) {
                int o = idx >> 6, b = idx & 63;
                const unsigned short* hp = h1 + (((size_t)(b >> 4) * 64 + lane) << 9) + (b & 15) * 8;
                const float* wp = fcw + (size_t)o * 2048 + lane * 32;
                float acc = 0.f;
                #pragma unroll
                for (int q = 0; q < 4; ++q) {
                    usvec8 hv = *(const usvec8*)(hp + q * 128);
                    vfloat4 w0 = *(const vfloat4*)(wp + q * 8);
                    vfloat4 w1 = *(const vfloat4*)(wp + q * 8 + 4);
                    acc = fmaf(bf2f(hv[0]), w0.x, acc);
                    acc = fmaf(bf2f(hv[1]), w0.y, acc);
                    acc = fmaf(bf2f(hv[2]), w0.z, acc);
                    acc = fmaf(bf2f(hv[3]), w0.w, acc);
                    acc = fmaf(bf2f(hv[4]), w1.x, acc);
                    acc = fmaf(bf2f(hv[5]), w1.y, acc);
                    acc = fmaf(bf2f(hv[6]), w1.z, acc);
                    acc = fmaf(bf2f(hv[7]), w1.w, acc);
                }
                #pragma unroll
                for (int off = 32; off; off >>= 1) acc += __shfl_xor(acc, off, 64);
                if (lane == 0) {
                    float v = fminf(1.f, fmaxf(-1.f, acc + fcb[o]));
                    outg[((size_t)b * 25 + (t - 1)) * 66 + o] = v;
                    xb[ap_idx(b, o, 3)] = f2bf(v);
                }
            }
        }
        if (t == 25) break;                  // final FC done; all blocks exit
        grid.sync();

        // ---------------- phase C0 (blocks 0..255) ----------------
        if (l == 0) {
            accv acc[4][2] = {};
            if (w < 3) {
                const unsigned short* bp = wih0p + (((size_t)(2 * jb) * 3 + w) << 9) + lane * 8;
                bfrag xw0 = LD8(bp), xw1 = LD8(bp + (3 << 9));
                #pragma unroll
                for (int mi = 0; mi < 4; ++mi) {
                    bfrag xa = LD8(xb + (((size_t)mi * 3 + w) << 9) + lane * 8);
                    acc[mi][0] = __builtin_amdgcn_mfma_f32_16x16x32_bf16(xa, xw0, acc[mi][0], 0, 0, 0);
                    acc[mi][1] = __builtin_amdgcn_mfma_f32_16x16x32_bf16(xa, xw1, acc[mi][1], 0, 0, 0);
                }
            }
            store_gsm(gsm, acc, lane, w);    // wave 3 stores zeros
            __syncthreads();
            #pragma unroll
            for (int half = 0; half < 2; ++half) {
                int it = half * 256 + tid;
                int b = it >> 3, jj = it & 7;
                const float* gpt = gp0 + (size_t)jb * 2048 + b * 32 + jj;
                float g4[4];
                #pragma unroll
                for (int g = 0; g < 4; ++g) {
                    int Cp = (g * 8 + jj) ^ ((b & 3) << 3);
                    g4[g] = gpt[g * 8] + gsm[0][b][Cp] + gsm[1][b][Cp] + gsm[2][b][Cp] + gsm[3][b][Cp];
                }
                int j = jb * 8 + jj;
                float iv = 1.f / (1.f + __expf(-(g4[0] + bsum0[j])));
                float fv = 1.f / (1.f + __expf(-(g4[1] + bsum0[2048 + j])));
                float gv = tanhf(g4[2] + bsum0[4096 + j]);
                float ov = 1.f / (1.f + __expf(-(g4[3] + bsum0[6144 + j])));
                float cold = half ? creg1 : creg0;
                float cn = fv * cold + iv * gv;
                float hn = ov * tanhf(cn);
                if (half) creg1 = cn; else creg0 = cn;
                h0[ap_idx(b, j, 64)] = f2bf(hn);
            }
        }
        grid.sync();

        // ---------------- phase C1 (blocks 256..511) ----------------
        if (l == 1) {
            accv acc[4][2] = {};
            gemmK<4>(h0, wih1p, jb, lane, w, acc);
            store_gsm(gsm, acc, lane, w);
            __syncthreads();
            #pragma unroll
            for (int half = 0; half < 2; ++half) {
                int it = half * 256 + tid;
                int b = it >> 3, jj = it & 7;
                const float* gpt = gp1 + (size_t)jb * 2048 + b * 32 + jj;
                float g4[4];
                #pragma unroll
                for (int g = 0; g < 4; ++g) {
                    int Cp = (g * 8 + jj) ^ ((b & 3) << 3);
                    g4[g] = gpt[g * 8] + gsm[0][b][Cp] + gsm[1][b][Cp] + gsm[2][b][Cp] + gsm[3][b][Cp];
                }
                int j = jb * 8 + jj;
                float iv = 1.f / (1.f + __expf(-(g4[0] + bsum1[j])));
                float fv = 1.f / (1.f + __expf(-(g4[1] + bsum1[2048 + j])));
                float gv = tanhf(g4[2] + bsum1[4096 + j]);
                float ov = 1.f / (1.f + __expf(-(g4[3] + bsum1[6144 + j])));
                float cold = half ? creg1 : creg0;
                float cn = fv * cold + iv * gv;
                float hn = ov * tanhf(cn);
                if (half) creg1 = cn; else creg0 = cn;
                h1[ap_idx(b, j, 64)] = f2bf(hn);
            }
        }
        grid.sync();
    }
}

// ---------------------------------------------------------------------------
extern "C" void kernel_launch(void* const* d_in, const int* in_sizes, int n_in,
                              void* d_out, int out_size, void* d_ws, size_t ws_size,
                              hipStream_t stream) {
    (void)in_sizes; (void)n_in; (void)out_size; (void)ws_size;
    const float* inputs  = (const float*)d_in[0];
    const float* hiddens = (const float*)d_in[1];
    const float* cells   = (const float*)d_in[2];
    const float* W_ih0   = (const float*)d_in[3];
    const float* W_hh0   = (const float*)d_in[4];
    const float* b_ih0   = (const float*)d_in[5];
    const float* b_hh0   = (const float*)d_in[6];
    const float* W_ih1   = (const float*)d_in[7];
    const float* W_hh1   = (const float*)d_in[8];
    const float* b_ih1   = (const float*)d_in[9];
    const float* b_hh1   = (const float*)d_in[10];
    const float* fc_w    = (const float*)d_in[11];
    const float* fc_b    = (const float*)d_in[12];
    float* out = (float*)d_out;

    // workspace layout (~108 MB)
    unsigned short* whh0p = (unsigned short*)d_ws;     // 16777216 shorts each
    unsigned short* wih1p = whh0p + 16777216;
    unsigned short* whh1p = wih1p + 16777216;
    unsigned short* wih0p = whh1p + 16777216;          // 786432 (Bp KC=3)
    unsigned short* h0    = wih0p + 786432;            // 131072 (Ap KC=64), in-place
    unsigned short* h1    = h0 + 131072;
    unsigned short* xb    = h1 + 131072;               // 6144 (Ap KC=3)
    float* c0    = (float*)(xb + 6144);                // 131072 fp32 each
    float* c1    = c0 + 131072;
    float* bsum0 = c1 + 131072;                        // 8192 fp32 each
    float* bsum1 = bsum0 + 8192;
    float* gp0   = bsum1 + 8192;                       // 524288 fp32 each (2 MB)
    float* gp1   = gp0 + 524288;

    prep<<<29784, 256, 0, stream>>>(W_hh0, W_ih1, W_hh1, whh0p, wih1p, whh1p,
                                    inputs, hiddens, cells, W_ih0,
                                    wih0p, h0, h1, c0, c1, xb,
                                    bsum0, bsum1, b_ih0, b_hh0, b_ih1, b_hh1);

    void* kargs[] = { (void*)&whh0p, (void*)&whh1p, (void*)&wih0p, (void*)&wih1p,
                      (void*)&h0, (void*)&h1, (void*)&c0, (void*)&c1,
                      (void*)&bsum0, (void*)&bsum1, (void*)&gp0, (void*)&gp1,
                      (void*)&xb, (void*)&fc_w, (void*)&fc_b, (void*)&out };
    hipLaunchCooperativeKernel((const void*)loopk, dim3(512), dim3(256),
                               kargs, 0, stream);
}